// Round 15
// baseline (256.984 us; speedup 1.0000x reference)
//
#include <hip/hip_runtime.h>

// ---------------------------------------------------------------------------
// SAGE 3-layer GNN.  (R22 = R21/R16 + intra-dispatch producer-consumer
//                     ticket chaining: 8 dispatches -> 5)
//   Per layer: S = X@W_self + b (fp32) ; P = X@W_neigh (bf16 row-major)
//              h[i] = act( S[i] + (sum_{j in N_in(i)} P[j]) / max(deg_i,1) )
//
// Evidence log:
//   R0..R5: random row-gather agg ~150us = per-CU gather service wall.
//   R9 WIN: src-bucket LDS slicing. R10 WIN: sorted-graph_id finish.
//   R11 WIN: one-pass fixed-cap CSR build. 255.9us.
//   R12/R13/R14: GLOBAL-barrier persistent kernel FAILED (capture kill;
//     per-poll-ACQUIRE L2-inval storm; coherence-traffic floor 441us).
//   R15 WIN (249.1): build+gemm1 merged; readout last-block-ticket fused.
//   R16 WIN (232.5): split-K wave-group GEMMs. BEST (reproduced R21: 234.2).
//   R17-R20: atomic-free planes + 3 GEMM-shape experiments all <= neutral.
//   R22 (this round): POINT-TO-POINT chaining (not a global barrier):
//     [agg1+gemm2] [agg2+gemm3] [agg3+finish+readout] single dispatches.
//     Gemm tile waits on: dtcnt[dtile]==8 (its rows' Hn final; agg block
//     bumps at retire after threadfence) AND pstg[bucket]==32 (its rows'
//     P slice fully STAGED by all readers -> safe to overwrite in place;
//     bumped right after agg's staging barrier). Finish waits dtcnt only.
//     Polls = RELAXED agent atomic loads (coherence point, no L2 effects,
//     R14-proven); ONE acquire fence per consumer block after exit.
//     Deadlock-free by counting: consumers (157/40) < 256 CUs, producers
//     never wait -> >=99 CUs always available to producers under ANY
//     dispatch order. Merged blocks 1024thr/160KB: gemm was <=1 block/CU
//     anyway (157<256) -> no concurrency lost.
//   Predicted: 234 -> ~215-228us. Regression/flaky -> revert R21, declare.
// ---------------------------------------------------------------------------

#define DH 64
#define NG 16
#define NSB 8        // src buckets
#define DTILES 32    // dst tiles -> 8*32 = 256 agg blocks (1/CU)
#define MAXNPB 1250  // max nodes per bucket (M <= 10000)
#define CAP 32       // edge slots per (dst,bucket) row; Poisson(4) tail ~1e-19
#define TILE_F 4352  // 64*68 floats per LDS tile
#define FB4 40       // finish blocks (16 waves each = 640 waves, R10 profile)

#define ACQ_FENCE() __builtin_amdgcn_fence(__ATOMIC_ACQUIRE, "agent")
#define RLX_LOAD(p) __hip_atomic_load((p), __ATOMIC_RELAXED, __HIP_MEMORY_SCOPE_AGENT)

__device__ __forceinline__ unsigned short f2bf(float f) {
    unsigned int u = __float_as_uint(f);
    unsigned int r = (u + 0x7FFFu + ((u >> 16) & 1u)) >> 16;   // RNE
    return (unsigned short)r;
}
__device__ __forceinline__ float bfu(unsigned short v) {
    return __uint_as_float(((unsigned int)v) << 16);
}
__device__ __forceinline__ int deg8(const int* __restrict__ cnt8, int n) {
    const int4* cp = reinterpret_cast<const int4*>(&cnt8[n * NSB]);
    int4 c0 = cp[0], c1 = cp[1];
    return c0.x + c0.y + c0.z + c0.w + c1.x + c1.y + c1.z + c1.w;
}

// ---- fused: layer-1 dual GEMM (blocks [0,gb)) + CSR build ([gb,gb+eb)) ----
// (byte-identical to R16/R21)
__global__ __launch_bounds__(512) void gemm1_build_kernel(
    const float* __restrict__ X, const float* __restrict__ Ws_g,
    const float* __restrict__ Wn_g, const float* __restrict__ bias,
    float* __restrict__ S, unsigned short* __restrict__ P,
    float* __restrict__ Hn_out,
    const int* __restrict__ src, const int* __restrict__ dst,
    int* __restrict__ cnt8, int* __restrict__ es,
    int M, int E, int npb8, int gb) {
    constexpr int K = 256;
    int tid = threadIdx.x;

    if ((int)blockIdx.x >= gb) {          // ---- build part ----
        int i = ((int)blockIdx.x - gb) * 512 + tid;
        if (i < E) {
            int s = src[i];
            int k = dst[i] * NSB + s / npb8;
            int p = atomicAdd(&cnt8[k], 1);
            if (p < CAP) es[(size_t)k * CAP + p] = s;   // clamp: memory-safe
        }
        return;
    }

    __shared__ float smem[6 * TILE_F];
    const int grp = tid >> 8;
    const int t   = tid & 255;
    const int cx = t & 15;
    const int ry = t >> 4;
    float* Xs  = smem + grp * 3 * TILE_F;
    float* Wsm = Xs + TILE_F;
    float* Wnm = Wsm + TILE_F;
    const int row0 = blockIdx.x * 64;
    float acc_s[4][4] = {{0.f}};
    float acc_n[4][4] = {{0.f}};

    for (int st = 0; st < 2; ++st) {
        const int kc = grp * 128 + st * 64;
#pragma unroll
        for (int it = 0; it < 4; ++it) {
            int q = t + 256 * it;
            int row = q >> 4;
            int k4 = (q & 15) * 4;
            float4 xv = make_float4(0.f, 0.f, 0.f, 0.f);
            int gr = row0 + row;
            if (gr < M)
                xv = *reinterpret_cast<const float4*>(&X[(size_t)gr * K + kc + k4]);
            *reinterpret_cast<float4*>(&Xs[row * 68 + k4]) = xv;
            *reinterpret_cast<float4*>(&Wsm[row * 68 + k4]) =
                *reinterpret_cast<const float4*>(&Ws_g[(size_t)(kc + row) * 64 + k4]);
            *reinterpret_cast<float4*>(&Wnm[row * 68 + k4]) =
                *reinterpret_cast<const float4*>(&Wn_g[(size_t)(kc + row) * 64 + k4]);
        }
        __syncthreads();
#pragma unroll 4
        for (int kk = 0; kk < 64; ++kk) {
            float av[4], bs[4], bn[4];
#pragma unroll
            for (int j = 0; j < 4; ++j) av[j] = Xs[(ry * 4 + j) * 68 + kk];
#pragma unroll
            for (int i = 0; i < 4; ++i) {
                bs[i] = Wsm[kk * 68 + cx + 16 * i];
                bn[i] = Wnm[kk * 68 + cx + 16 * i];
            }
#pragma unroll
            for (int j = 0; j < 4; ++j)
#pragma unroll
                for (int i = 0; i < 4; ++i) {
                    acc_s[j][i] += av[j] * bs[i];
                    acc_n[j][i] += av[j] * bn[i];
                }
        }
        __syncthreads();
    }

    float* flat = smem + 3 * TILE_F;
    if (grp == 1) {
        int o = t * 33;
#pragma unroll
        for (int j = 0; j < 4; ++j)
#pragma unroll
            for (int i = 0; i < 4; ++i) {
                flat[o + j * 4 + i]      = acc_s[j][i];
                flat[o + 16 + j * 4 + i] = acc_n[j][i];
            }
    }
    __syncthreads();
    if (grp == 0) {
        int o = t * 33;
#pragma unroll
        for (int j = 0; j < 4; ++j)
#pragma unroll
            for (int i = 0; i < 4; ++i) {
                acc_s[j][i] += flat[o + j * 4 + i];
                acc_n[j][i] += flat[o + 16 + j * 4 + i];
            }
#pragma unroll
        for (int j = 0; j < 4; ++j) {
            int r = row0 + ry * 4 + j;
            if (r < M) {
#pragma unroll
                for (int i = 0; i < 4; ++i) {
                    int col = cx + 16 * i;
                    S[(size_t)r * DH + col] = acc_s[j][i] + bias[col];
                    P[(size_t)r * DH + col] = f2bf(acc_n[j][i]);
                    Hn_out[(size_t)r * DH + col] = 0.f;
                }
            }
        }
    }
}

// ---- agg role (1024 thr): R21 agg body + stage/retire tickets -------------
__device__ void agg_role(const unsigned short* __restrict__ P,
                         const int* __restrict__ cnt8, const int* __restrict__ es,
                         float* __restrict__ Hn, int M, int npb8, int bid,
                         int* __restrict__ dtcnt, int* __restrict__ pstg,
                         char* smemraw) {
    unsigned short* sP = reinterpret_cast<unsigned short*>(smemraw);
    int tid = threadIdx.x;
    int sb    = bid & (NSB - 1);
    int dtile = bid >> 3;
    int s0 = sb * npb8;
    int snodes = min(npb8, M - s0);

    {   // stage this bucket's P slice (coalesced uint4)
        const uint4* gp = reinterpret_cast<const uint4*>(P + (size_t)s0 * DH);
        int cnt = snodes * 8;
        for (int j = tid; j < cnt; j += 1024)
            *reinterpret_cast<uint4*>(&sP[j * 8]) = gp[j];
    }
    __syncthreads();
    // staging done: this block will never read P again -> publish.
    if (tid == 0)
        __hip_atomic_fetch_add(&pstg[sb], 1, __ATOMIC_RELAXED, __HIP_MEMORY_SCOPE_AGENT);

    int lane = tid & 63, wid = tid >> 6;
    int dpb  = (M + DTILES - 1) / DTILES;
    int d0t  = dtile * dpb;
    int dend = min(d0t + dpb, M);

    for (int dstn = d0t + wid; dstn < dend; dstn += 16) {
        int key = dstn * NSB + sb;
        int cnt = min(cnt8[key], CAP);
        if (cnt == 0) continue;
        size_t base = (size_t)key * CAP;
        float acc = 0.f;
        int cmax = cnt - 1;
        for (int e = 0; e < cnt; e += 4) {
            int i0 = es[base + min(e + 0, cmax)] - s0;
            int i1 = es[base + min(e + 1, cmax)] - s0;
            int i2 = es[base + min(e + 2, cmax)] - s0;
            int i3 = es[base + min(e + 3, cmax)] - s0;
            float m1 = (e + 1 < cnt) ? 1.f : 0.f;
            float m2 = (e + 2 < cnt) ? 1.f : 0.f;
            float m3 = (e + 3 < cnt) ? 1.f : 0.f;
            float f0 = bfu(sP[(size_t)i0 * DH + lane]);
            float f1 = bfu(sP[(size_t)i1 * DH + lane]);
            float f2 = bfu(sP[(size_t)i2 * DH + lane]);
            float f3 = bfu(sP[(size_t)i3 * DH + lane]);
            acc += f0;
            acc = fmaf(m1, f1, acc);
            acc = fmaf(m2, f2, acc);
            acc = fmaf(m3, f3, acc);
        }
        atomicAdd(&Hn[(size_t)dstn * DH + lane], acc);   // coalesced 256 B
    }
    // all Hn adds for this (bucket, dtile) complete -> publish retirement.
    __syncthreads();   // drains vmcnt for all waves
    if (tid == 0) {
        __threadfence();   // release: order Hn atomics before ticket
        __hip_atomic_fetch_add(&dtcnt[dtile], 1, __ATOMIC_RELAXED, __HIP_MEMORY_SCOPE_AGENT);
    }
}

// ---- gemm role (tid<512 active; 1024-thr block): R16 K=64 body + waits ----
__device__ void gemm_role(const float* __restrict__ Ws_g,
                          const float* __restrict__ Wn_g,
                          const float* __restrict__ bias,
                          const int* __restrict__ cnt8,
                          float* __restrict__ S, unsigned short* __restrict__ P,
                          float* __restrict__ Hn, int M, int npb8, int tile,
                          int* __restrict__ dtcnt, int* __restrict__ pstg,
                          char* smemraw) {
    float* smem = reinterpret_cast<float*>(smemraw);
    int tid = threadIdx.x;
    const int row0 = tile * 64;
    const int dpb = (M + DTILES - 1) / DTILES;

    if (tid == 0) {   // wait: Hn final for my dtiles; P slices staged for my buckets
        int d0 = row0 / dpb, d1 = min((row0 + 63) / dpb, DTILES - 1);
        int b0 = row0 / npb8, b1 = min((row0 + 63) / npb8, NSB - 1);
        while (RLX_LOAD(&dtcnt[d0]) < NSB) __builtin_amdgcn_s_sleep(8);
        if (d1 != d0)
            while (RLX_LOAD(&dtcnt[d1]) < NSB) __builtin_amdgcn_s_sleep(8);
        while (RLX_LOAD(&pstg[b0]) < DTILES) __builtin_amdgcn_s_sleep(8);
        if (b1 != b0)
            while (RLX_LOAD(&pstg[b1]) < DTILES) __builtin_amdgcn_s_sleep(8);
        ACQ_FENCE();   // drop stale L2 lines exactly once
    }
    __syncthreads();

    const int grp = tid >> 8;             // 0 / 1 (tid<512)
    const int t   = tid & 255;
    const int cx = t & 15;
    const int ry = t >> 4;
    float* Xs  = smem;
    float* Wsm = smem + TILE_F;
    float* Wnm = smem + 2 * TILE_F;
    float acc_s[4][4] = {{0.f}};
    float acc_n[4][4] = {{0.f}};

    if (tid < 512) {   // stage (2 passes cover 64 rows x 16 k4-groups)
#pragma unroll
        for (int it = 0; it < 2; ++it) {
            int q = tid + 512 * it;
            int row = q >> 4;
            int k4 = (q & 15) * 4;
            float4 xv = make_float4(0.f, 0.f, 0.f, 0.f);
            int gr = row0 + row;
            if (gr < M) {
                xv = *reinterpret_cast<const float4*>(&S[(size_t)gr * DH + k4]);
                float4 hv = *reinterpret_cast<const float4*>(&Hn[(size_t)gr * DH + k4]);
                float inv = 1.f / fmaxf((float)deg8(cnt8, gr), 1.f);
                xv.x = fmaxf(fmaf(hv.x, inv, xv.x), 0.f);
                xv.y = fmaxf(fmaf(hv.y, inv, xv.y), 0.f);
                xv.z = fmaxf(fmaf(hv.z, inv, xv.z), 0.f);
                xv.w = fmaxf(fmaf(hv.w, inv, xv.w), 0.f);
            }
            *reinterpret_cast<float4*>(&Xs[row * 68 + k4]) = xv;
            *reinterpret_cast<float4*>(&Wsm[row * 68 + k4]) =
                *reinterpret_cast<const float4*>(&Ws_g[(size_t)row * 64 + k4]);
            *reinterpret_cast<float4*>(&Wnm[row * 68 + k4]) =
                *reinterpret_cast<const float4*>(&Wn_g[(size_t)row * 64 + k4]);
        }
    }
    __syncthreads();
    if (tid < 512) {
        const int kk0 = grp * 32;
#pragma unroll 4
        for (int kk = kk0; kk < kk0 + 32; ++kk) {
            float av[4], bs[4], bn[4];
#pragma unroll
            for (int j = 0; j < 4; ++j) av[j] = Xs[(ry * 4 + j) * 68 + kk];
#pragma unroll
            for (int i = 0; i < 4; ++i) {
                bs[i] = Wsm[kk * 68 + cx + 16 * i];
                bn[i] = Wnm[kk * 68 + cx + 16 * i];
            }
#pragma unroll
            for (int j = 0; j < 4; ++j)
#pragma unroll
                for (int i = 0; i < 4; ++i) {
                    acc_s[j][i] += av[j] * bs[i];
                    acc_n[j][i] += av[j] * bn[i];
                }
        }
    }
    __syncthreads();   // all reads of Xs/Ws/Wn done -> safe to reuse

    if (tid < 512 && (tid >> 8) == 1) {   // grp1 dumps partials, stride 33
        int o = t * 33;
#pragma unroll
        for (int j = 0; j < 4; ++j)
#pragma unroll
            for (int i = 0; i < 4; ++i) {
                smem[o + j * 4 + i]      = acc_s[j][i];
                smem[o + 16 + j * 4 + i] = acc_n[j][i];
            }
    }
    __syncthreads();
    if (tid < 256) {   // grp0 combines + epilogue
        int o = t * 33;
#pragma unroll
        for (int j = 0; j < 4; ++j)
#pragma unroll
            for (int i = 0; i < 4; ++i) {
                acc_s[j][i] += smem[o + j * 4 + i];
                acc_n[j][i] += smem[o + 16 + j * 4 + i];
            }
#pragma unroll
        for (int j = 0; j < 4; ++j) {
            int r = row0 + ry * 4 + j;
            if (r < M) {
#pragma unroll
                for (int i = 0; i < 4; ++i) {
                    int col = cx + 16 * i;
                    S[(size_t)r * DH + col] = acc_s[j][i] + bias[col];
                    P[(size_t)r * DH + col] = f2bf(acc_n[j][i]);
                    Hn[(size_t)r * DH + col] = 0.f;
                }
            }
        }
    }
}

// ---- merged dispatch: agg layer-N (blocks [0,ab)) + gemm layer-N+1 --------
__global__ __launch_bounds__(1024) void agg_gemm_kernel(
    unsigned short* __restrict__ P, const int* __restrict__ cnt8,
    const int* __restrict__ es, float* __restrict__ Hn,
    const float* __restrict__ Ws_g, const float* __restrict__ Wn_g,
    const float* __restrict__ bias, float* __restrict__ S,
    int* __restrict__ dtcnt, int* __restrict__ pstg,
    int M, int npb8, int ab) {
    __shared__ __align__(16) char smemraw[160000];
    if ((int)blockIdx.x < ab)
        agg_role(P, cnt8, es, Hn, M, npb8, blockIdx.x, dtcnt, pstg, smemraw);
    else
        gemm_role(Ws_g, Wn_g, bias, cnt8, S, P, Hn, M, npb8,
                  blockIdx.x - ab, dtcnt, pstg, smemraw);
}

// ---- merged dispatch: agg layer-3 + finish + readout ----------------------
__global__ __launch_bounds__(1024) void agg_finish_kernel(
    unsigned short* __restrict__ P, const int* __restrict__ cnt8,
    const int* __restrict__ es, float* __restrict__ Hn,
    const float* __restrict__ S, const int* __restrict__ graph_id,
    float* __restrict__ H, float* __restrict__ gsum, float* __restrict__ gcnt,
    const float* __restrict__ Wc, const float* __restrict__ bc,
    float* __restrict__ out, float* __restrict__ out_feat,
    unsigned int* __restrict__ done, int* __restrict__ dtcnt,
    int* __restrict__ pstg, int M, int npb8, int ab) {
    __shared__ __align__(16) char smemraw[160000];
    int tid = threadIdx.x;
    if ((int)blockIdx.x < ab) {
        agg_role(P, cnt8, es, Hn, M, npb8, blockIdx.x, dtcnt, pstg, smemraw);
        return;
    }
    // ---- finish role: 16 waves x cpw nodes; block covers 256 nodes ----
    int fbid = blockIdx.x - ab;
    int dpb = (M + DTILES - 1) / DTILES;
    if (tid == 0) {
        int nlo = fbid * 256;
        int d0 = min(nlo / dpb, DTILES - 1);
        int d1 = min((nlo + 255) / dpb, DTILES - 1);
        while (RLX_LOAD(&dtcnt[d0]) < NSB) __builtin_amdgcn_s_sleep(8);
        if (d1 != d0)
            while (RLX_LOAD(&dtcnt[d1]) < NSB) __builtin_amdgcn_s_sleep(8);
        ACQ_FENCE();
    }
    __syncthreads();

    int lane = tid & 63, wvl = tid >> 6;
    {
        int wid = fbid * 16 + wvl;
        int nw  = FB4 * 16;
        int cpw = (M + nw - 1) / nw;      // 16
        int n0 = wid * cpw, n1 = min(n0 + cpw, M);
        if (n0 < n1) {
            float acc = 0.f;
            int cnt = 0;
            int cur = graph_id[n0];
            for (int n = n0; n < n1; ++n) {
                int gid = graph_id[n];
                if (gid != cur) {
                    atomicAdd(&gsum[cur * DH + lane], acc);
                    if (lane == 0) atomicAdd(&gcnt[cur], (float)cnt);
                    acc = 0.f; cnt = 0; cur = gid;
                }
                float inv = 1.f / fmaxf((float)deg8(cnt8, n), 1.f);
                size_t o = (size_t)n * DH + lane;
                float val = fmaf(Hn[o], inv, S[o]);
                H[o] = val;
                acc += val;
                ++cnt;
            }
            atomicAdd(&gsum[cur * DH + lane], acc);
            if (lane == 0) atomicAdd(&gcnt[cur], (float)cnt);
        }
    }

    // ---- last-finish-block ticket (among FB4 blocks) ----
    float* ofs = reinterpret_cast<float*>(smemraw);               // [NG*DH]
    unsigned int* s_ticket = reinterpret_cast<unsigned int*>(smemraw + NG * DH * 4);
    __syncthreads();
    if (tid == 0) {
        __threadfence();   // release: publish gsum/gcnt/H
        *s_ticket = __hip_atomic_fetch_add(done, 1u, __ATOMIC_ACQ_REL,
                                           __HIP_MEMORY_SCOPE_AGENT);
    }
    __syncthreads();
    if (*s_ticket != (unsigned int)(FB4 - 1)) return;
    if (tid == 0) __threadfence();   // acquire: see all blocks' gsum/gcnt
    __syncthreads();

    // ---- readout by the last block (1024 threads, 1 entry each) ----
    {
        int g = tid >> 6;
        float of = gsum[tid] / fmaxf(gcnt[g], 1.0f);
        out_feat[tid] = of;
        ofs[tid] = of;
    }
    __syncthreads();
    if (tid < NG * 2) {
        int gg = tid >> 1, cc = tid & 1;
        float accv = bc[cc];
#pragma unroll 8
        for (int dd = 0; dd < DH; ++dd) accv += ofs[gg * DH + dd] * Wc[dd * 2 + cc];
        out[gg * 2 + cc] = accv;
    }
}

extern "C" void kernel_launch(void* const* d_in, const int* in_sizes, int n_in,
                              void* d_out, int out_size, void* d_ws, size_t ws_size,
                              hipStream_t stream) {
    const float* feat     = (const float*)d_in[0];
    const int*   src      = (const int*)d_in[1];
    const int*   dst      = (const int*)d_in[2];
    const int*   graph_id = (const int*)d_in[3];
    const float* Ws1 = (const float*)d_in[4];
    const float* Wn1 = (const float*)d_in[5];
    const float* b1  = (const float*)d_in[6];
    const float* Ws2 = (const float*)d_in[7];
    const float* Wn2 = (const float*)d_in[8];
    const float* b2  = (const float*)d_in[9];
    const float* Ws3 = (const float*)d_in[10];
    const float* Wn3 = (const float*)d_in[11];
    const float* b3  = (const float*)d_in[12];
    const float* Wc  = (const float*)d_in[13];
    const float* bc  = (const float*)d_in[14];

    const int M  = in_sizes[3];     // 10000 nodes
    const int E  = in_sizes[1];     // 320000 edges
    const int M2 = M * NSB;         // 80000 (dst,bucket) rows
    const int npb8 = (M + NSB - 1) / NSB;   // 1250 (<= MAXNPB)

    float* out      = (float*)d_out;             // 16 x 2
    float* out_feat = out + NG * 2;              // 16 x 64
    float* Hbuf     = out_feat + NG * DH;        // 10000 x 64 (final h)

    // workspace layout (256B-aligned carves)
    char* w = (char*)d_ws;
    size_t off = 0;
    auto carve = [&](size_t bytes) {
        size_t o = off;
        off = (off + bytes + 255) & ~(size_t)255;
        return o;
    };
    int*   cnt8  = (int*)  (w + carve((size_t)M2 * 4));
    float* gsum  = (float*)(w + carve((size_t)NG * DH * 4));
    float* gcnt  = (float*)(w + carve((size_t)NG * 4));
    unsigned int* done = (unsigned int*)(w + carve(4));
    int*   dt1   = (int*)  (w + carve(DTILES * 4));
    int*   dt2   = (int*)  (w + carve(DTILES * 4));
    int*   dt3   = (int*)  (w + carve(DTILES * 4));
    int*   ps1   = (int*)  (w + carve(NSB * 4));
    int*   ps2   = (int*)  (w + carve(NSB * 4));
    int*   ps3   = (int*)  (w + carve(NSB * 4));
    size_t zero_bytes = off;           // cnt8+gsum+gcnt+done+tickets
    int*   es    = (int*)  (w + carve((size_t)M2 * CAP * 4));   // 10.24 MB
    float* Sbuf  = (float*)(w + carve((size_t)M * DH * 4));
    unsigned short* Pbuf = (unsigned short*)(w + carve((size_t)M * DH * 2));
    float* Hn    = (float*)(w + carve((size_t)M * DH * 4));
    (void)ws_size; (void)n_in; (void)out_size;

    (void)hipMemsetAsync(d_ws, 0, zero_bytes, stream);

    int gb = (M + 63) / 64;          // 157 gemm blocks
    int eb = (E + 511) / 512;        // 625 build blocks (512 thr)
    int ab = NSB * DTILES;           // 256 agg blocks

    // layer 1 (K=256, split-K) + CSR build, ONE dispatch
    gemm1_build_kernel<<<gb + eb, 512, 0, stream>>>(
        feat, Ws1, Wn1, b1, Sbuf, Pbuf, Hn,
        src, dst, cnt8, es, M, E, npb8, gb);

    // agg1 + gemm2 (ticket-chained, one dispatch)
    agg_gemm_kernel<<<ab + gb, 1024, 0, stream>>>(
        Pbuf, cnt8, es, Hn, Ws2, Wn2, b2, Sbuf, dt1, ps1, M, npb8, ab);

    // agg2 + gemm3
    agg_gemm_kernel<<<ab + gb, 1024, 0, stream>>>(
        Pbuf, cnt8, es, Hn, Ws3, Wn3, b3, Sbuf, dt2, ps2, M, npb8, ab);

    // agg3 + finish + readout
    agg_finish_kernel<<<ab + FB4, 1024, 0, stream>>>(
        Pbuf, cnt8, es, Hn, Sbuf, graph_id, Hbuf, gsum, gcnt,
        Wc, bc, out, out_feat, done, dt3, ps3, M, npb8, ab);
}

// Round 17
// 231.722 us; speedup vs baseline: 1.1090x; 1.1090x over previous
//
#include <hip/hip_runtime.h>

// ---------------------------------------------------------------------------
// SAGE 3-layer GNN.  (R24 = R16 pipeline, ticket readout -> own dispatch)
//   Per layer: S = X@W_self + b (fp32) ; P = X@W_neigh (bf16 row-major)
//              h[i] = act( S[i] + (sum_{j in N_in(i)} P[j]) / max(deg_i,1) )
//
// FINAL STRUCTURE: one-pass fixed-cap CSR build fused into gemm1 dispatch
// (R11/R15, independent outputs -> no cross-block comm) -> src-bucket
// LDS-sliced agg with coalesced 256B Hn atomics (R9) -> split-K wave-group
// dual GEMMs with fused relu(S+Hn/deg) loader (R16) -> sorted-graph_id
// register-accumulated finish (R10) -> separate single-block readout.
// 9 dispatches; ALL inter-block dependences stream-ordered.
//
// R23 failure analysis: post-timing divergence (1-in-4 runs) — the only
// non-stream-ordered sync in the design was the finish kernel's last-block
// ticket (device atomic + divergent threadfence acquire for cross-XCD
// visibility of plain gsum loads on non-coherent L2s). Removed: readout is
// its own dispatch again (+~3us, the R15-measured boundary cost). No
// device-scope fence/spin/ticket constructs remain anywhere.
//
// Measured-and-rejected alternatives: grid-wide-sync persistent kernel
// (R12 capture kill / R13 821us L2-inval storm / R14 441us coherence
// floor); point-to-point ticket chaining (R22, 257us); atomic-free partial
// planes (R17 259 / R18 236.8); GEMM reshapes (R19 234.9 / R20 236.0).
//
// Convergence: dur ~236 = ~43us harness re-poison fill (inside dur_us,
// 80% HBM, immovable) + 8 dependent dispatches each too small to fill
// 256 CUs + launch gaps. At M=10k/E=320k per-phase work (~0.7 GFLOP,
// ~30MB) cannot fill this machine; every overlap mechanism costs more in
// cross-XCD coherence than it recovers.
// ---------------------------------------------------------------------------

#define DH 64
#define NG 16
#define NSB 8        // src buckets
#define DTILES 32    // dst tiles -> grid 8*32 = 256 agg blocks (1/CU)
#define MAXNPB 1250  // max nodes per bucket (M <= 10000)
#define CAP 32       // edge slots per (dst,bucket) row; Poisson(4) tail ~1e-19
#define TILE_F 4352  // 64*68 floats per LDS tile

__device__ __forceinline__ unsigned short f2bf(float f) {
    unsigned int u = __float_as_uint(f);
    unsigned int r = (u + 0x7FFFu + ((u >> 16) & 1u)) >> 16;   // RNE
    return (unsigned short)r;
}
__device__ __forceinline__ float bfu(unsigned short v) {
    return __uint_as_float(((unsigned int)v) << 16);
}
__device__ __forceinline__ int deg8(const int* __restrict__ cnt8, int n) {
    const int4* cp = reinterpret_cast<const int4*>(&cnt8[n * NSB]);
    int4 c0 = cp[0], c1 = cp[1];
    return c0.x + c0.y + c0.z + c0.w + c1.x + c1.y + c1.z + c1.w;
}

// ---- fused: layer-1 dual GEMM (blocks [0,gb)) + CSR build ([gb,gb+eb)) ----
// gemm: split-K wave groups — grp0 kc{0,64}, grp1 kc{128,192}, private LDS;
// grp1 dumps fp32 partials to its (dead) LDS region stride-33 (bank-free);
// grp0 adds + epilogue (S, P, Hn=0).
// build: one edge per thread, p=atomicAdd(cnt8[key]); es[key*CAP+p]=src.
__global__ __launch_bounds__(512) void gemm1_build_kernel(
    const float* __restrict__ X, const float* __restrict__ Ws_g,
    const float* __restrict__ Wn_g, const float* __restrict__ bias,
    float* __restrict__ S, unsigned short* __restrict__ P,
    float* __restrict__ Hn_out,
    const int* __restrict__ src, const int* __restrict__ dst,
    int* __restrict__ cnt8, int* __restrict__ es,
    int M, int E, int npb8, int gb) {
    constexpr int K = 256;
    int tid = threadIdx.x;

    if ((int)blockIdx.x >= gb) {          // ---- build part ----
        int i = ((int)blockIdx.x - gb) * 512 + tid;
        if (i < E) {
            int s = src[i];
            int k = dst[i] * NSB + s / npb8;
            int p = atomicAdd(&cnt8[k], 1);
            if (p < CAP) es[(size_t)k * CAP + p] = s;   // clamp: memory-safe
        }
        return;
    }

    // ---- gemm part: split-K over 2 wave groups ----
    __shared__ float smem[6 * TILE_F];    // grp0: Xs,Ws,Wn ; grp1: Xs,Ws,Wn
    const int grp = tid >> 8;             // 0: waves 0-3, 1: waves 4-7
    const int t   = tid & 255;
    const int cx = t & 15;
    const int ry = t >> 4;
    float* Xs  = smem + grp * 3 * TILE_F;
    float* Wsm = Xs + TILE_F;
    float* Wnm = Wsm + TILE_F;
    const int row0 = blockIdx.x * 64;
    float acc_s[4][4] = {{0.f}};
    float acc_n[4][4] = {{0.f}};

    for (int st = 0; st < 2; ++st) {
        const int kc = grp * 128 + st * 64;
#pragma unroll
        for (int it = 0; it < 4; ++it) {
            int q = t + 256 * it;         // 0..1023
            int row = q >> 4;
            int k4 = (q & 15) * 4;
            float4 xv = make_float4(0.f, 0.f, 0.f, 0.f);
            int gr = row0 + row;
            if (gr < M)
                xv = *reinterpret_cast<const float4*>(&X[(size_t)gr * K + kc + k4]);
            *reinterpret_cast<float4*>(&Xs[row * 68 + k4]) = xv;
            *reinterpret_cast<float4*>(&Wsm[row * 68 + k4]) =
                *reinterpret_cast<const float4*>(&Ws_g[(size_t)(kc + row) * 64 + k4]);
            *reinterpret_cast<float4*>(&Wnm[row * 68 + k4]) =
                *reinterpret_cast<const float4*>(&Wn_g[(size_t)(kc + row) * 64 + k4]);
        }
        __syncthreads();
#pragma unroll 4
        for (int kk = 0; kk < 64; ++kk) {
            float av[4], bs[4], bn[4];
#pragma unroll
            for (int j = 0; j < 4; ++j) av[j] = Xs[(ry * 4 + j) * 68 + kk];
#pragma unroll
            for (int i = 0; i < 4; ++i) {
                bs[i] = Wsm[kk * 68 + cx + 16 * i];
                bn[i] = Wnm[kk * 68 + cx + 16 * i];
            }
#pragma unroll
            for (int j = 0; j < 4; ++j)
#pragma unroll
                for (int i = 0; i < 4; ++i) {
                    acc_s[j][i] += av[j] * bs[i];
                    acc_n[j][i] += av[j] * bn[i];
                }
        }
        __syncthreads();
    }

    // combine: grp1 -> its own (dead) LDS region, stride 33 (bank-free)
    float* flat = smem + 3 * TILE_F;
    if (grp == 1) {
        int o = t * 33;
#pragma unroll
        for (int j = 0; j < 4; ++j)
#pragma unroll
            for (int i = 0; i < 4; ++i) {
                flat[o + j * 4 + i]      = acc_s[j][i];
                flat[o + 16 + j * 4 + i] = acc_n[j][i];
            }
    }
    __syncthreads();
    if (grp == 0) {
        int o = t * 33;
#pragma unroll
        for (int j = 0; j < 4; ++j)
#pragma unroll
            for (int i = 0; i < 4; ++i) {
                acc_s[j][i] += flat[o + j * 4 + i];
                acc_n[j][i] += flat[o + 16 + j * 4 + i];
            }
#pragma unroll
        for (int j = 0; j < 4; ++j) {
            int r = row0 + ry * 4 + j;
            if (r < M) {
#pragma unroll
                for (int i = 0; i < 4; ++i) {
                    int col = cx + 16 * i;
                    S[(size_t)r * DH + col] = acc_s[j][i] + bias[col];
                    P[(size_t)r * DH + col] = f2bf(acc_n[j][i]);
                    Hn_out[(size_t)r * DH + col] = 0.f;
                }
            }
        }
    }
}

// ---- dual GEMM layers 2/3 (K=64): X = relu(S + Hn/deg) fused on load ------
// 512 threads: all stage the single 64x64 tile-set once; grp0 computes
// kk 0-31, grp1 kk 32-63; combine via stride-33 LDS reuse; grp0 epilogue.
// In-place S/Hn is block-safe: each block reads only its own 64 rows
// (barrier-ordered) before writing them; blocks own disjoint rows.
__global__ __launch_bounds__(512) void gemm_dual_kernel(
    const float* __restrict__ X, const float* __restrict__ Ws_g,
    const float* __restrict__ Wn_g, const float* __restrict__ bias,
    const float* __restrict__ Hn_in, const int* __restrict__ cnt8,
    float* __restrict__ S, unsigned short* __restrict__ P,
    float* __restrict__ Hn_out, int M) {
    constexpr int K = 64;
    __shared__ float smem[3 * TILE_F];    // Xs, Ws, Wn (combine reuses base)
    int tid = threadIdx.x;
    const int grp = tid >> 8;
    const int t   = tid & 255;
    const int cx = t & 15;
    const int ry = t >> 4;
    float* Xs  = smem;
    float* Wsm = smem + TILE_F;
    float* Wnm = smem + 2 * TILE_F;
    const int row0 = blockIdx.x * 64;
    float acc_s[4][4] = {{0.f}};
    float acc_n[4][4] = {{0.f}};

    {   // stage by all 512 threads (2 passes cover 64 rows x 16 k4-groups)
#pragma unroll
        for (int it = 0; it < 2; ++it) {
            int q = tid + 512 * it;       // 0..1023
            int row = q >> 4;
            int k4 = (q & 15) * 4;
            float4 xv = make_float4(0.f, 0.f, 0.f, 0.f);
            int gr = row0 + row;
            if (gr < M) {
                xv = *reinterpret_cast<const float4*>(&X[(size_t)gr * K + k4]);
                float4 hv = *reinterpret_cast<const float4*>(&Hn_in[(size_t)gr * DH + k4]);
                float inv = 1.f / fmaxf((float)deg8(cnt8, gr), 1.f);
                xv.x = fmaxf(fmaf(hv.x, inv, xv.x), 0.f);
                xv.y = fmaxf(fmaf(hv.y, inv, xv.y), 0.f);
                xv.z = fmaxf(fmaf(hv.z, inv, xv.z), 0.f);
                xv.w = fmaxf(fmaf(hv.w, inv, xv.w), 0.f);
            }
            *reinterpret_cast<float4*>(&Xs[row * 68 + k4]) = xv;
            *reinterpret_cast<float4*>(&Wsm[row * 68 + k4]) =
                *reinterpret_cast<const float4*>(&Ws_g[(size_t)row * 64 + k4]);
            *reinterpret_cast<float4*>(&Wnm[row * 68 + k4]) =
                *reinterpret_cast<const float4*>(&Wn_g[(size_t)row * 64 + k4]);
        }
        __syncthreads();
        const int kk0 = grp * 32;
#pragma unroll 4
        for (int kk = kk0; kk < kk0 + 32; ++kk) {
            float av[4], bs[4], bn[4];
#pragma unroll
            for (int j = 0; j < 4; ++j) av[j] = Xs[(ry * 4 + j) * 68 + kk];
#pragma unroll
            for (int i = 0; i < 4; ++i) {
                bs[i] = Wsm[kk * 68 + cx + 16 * i];
                bn[i] = Wnm[kk * 68 + cx + 16 * i];
            }
#pragma unroll
            for (int j = 0; j < 4; ++j)
#pragma unroll
                for (int i = 0; i < 4; ++i) {
                    acc_s[j][i] += av[j] * bs[i];
                    acc_n[j][i] += av[j] * bn[i];
                }
        }
        __syncthreads();   // all reads of Xs/Ws/Wn done -> safe to reuse
    }

    // combine: grp1 partials into reused smem base, stride 33
    if (grp == 1) {
        int o = t * 33;
#pragma unroll
        for (int j = 0; j < 4; ++j)
#pragma unroll
            for (int i = 0; i < 4; ++i) {
                smem[o + j * 4 + i]      = acc_s[j][i];
                smem[o + 16 + j * 4 + i] = acc_n[j][i];
            }
    }
    __syncthreads();
    if (grp == 0) {
        int o = t * 33;
#pragma unroll
        for (int j = 0; j < 4; ++j)
#pragma unroll
            for (int i = 0; i < 4; ++i) {
                acc_s[j][i] += smem[o + j * 4 + i];
                acc_n[j][i] += smem[o + 16 + j * 4 + i];
            }
#pragma unroll
        for (int j = 0; j < 4; ++j) {
            int r = row0 + ry * 4 + j;
            if (r < M) {
#pragma unroll
                for (int i = 0; i < 4; ++i) {
                    int col = cx + 16 * i;
                    S[(size_t)r * DH + col] = acc_s[j][i] + bias[col];
                    P[(size_t)r * DH + col] = f2bf(acc_n[j][i]);
                    Hn_out[(size_t)r * DH + col] = 0.f;
                }
            }
        }
    }
}

// ---- aggregation: src-bucket LDS slice, wave-per-(dst,bucket) row ----------
// grid = NSB * DTILES blocks x 1024 threads. LDS = 1250*64 bf16 = 160,000 B.
__global__ __launch_bounds__(1024) void agg_kernel(
    const unsigned short* __restrict__ P, const int* __restrict__ cnt8,
    const int* __restrict__ es, float* __restrict__ Hn, int M, int npb8) {
    __shared__ __align__(16) unsigned short sP[MAXNPB * DH];
    int tid = threadIdx.x;
    int sb    = blockIdx.x & (NSB - 1);
    int dtile = blockIdx.x >> 3;
    int s0 = sb * npb8;
    int snodes = min(npb8, M - s0);

    // stage this bucket's P slice (coalesced uint4)
    {
        const uint4* gp = reinterpret_cast<const uint4*>(P + (size_t)s0 * DH);
        int cnt = snodes * 8;   // 128 B/node / 16 B
        for (int j = tid; j < cnt; j += 1024)
            *reinterpret_cast<uint4*>(&sP[j * 8]) = gp[j];
    }
    __syncthreads();

    int lane = tid & 63, wid = tid >> 6;
    int dpb  = (M + DTILES - 1) / DTILES;
    int d0t  = dtile * dpb;
    int dend = min(d0t + dpb, M);

    for (int dstn = d0t + wid; dstn < dend; dstn += 16) {
        int key = dstn * NSB + sb;
        int cnt = min(cnt8[key], CAP);
        if (cnt == 0) continue;
        size_t base = (size_t)key * CAP;
        float acc = 0.f;
        int cmax = cnt - 1;
        for (int e = 0; e < cnt; e += 4) {
            int i0 = es[base + min(e + 0, cmax)] - s0;
            int i1 = es[base + min(e + 1, cmax)] - s0;
            int i2 = es[base + min(e + 2, cmax)] - s0;
            int i3 = es[base + min(e + 3, cmax)] - s0;
            float m1 = (e + 1 < cnt) ? 1.f : 0.f;
            float m2 = (e + 2 < cnt) ? 1.f : 0.f;
            float m3 = (e + 3 < cnt) ? 1.f : 0.f;
            float f0 = bfu(sP[(size_t)i0 * DH + lane]);
            float f1 = bfu(sP[(size_t)i1 * DH + lane]);
            float f2 = bfu(sP[(size_t)i2 * DH + lane]);
            float f3 = bfu(sP[(size_t)i3 * DH + lane]);
            acc += f0;                       // e+0 always valid in-loop
            acc = fmaf(m1, f1, acc);
            acc = fmaf(m2, f2, acc);
            acc = fmaf(m3, f3, acc);
        }
        atomicAdd(&Hn[(size_t)dstn * DH + lane], acc);   // coalesced 256 B
    }
}

// ---- layer-3 finish: H = S + Hn/deg (no relu) + readout accumulation ------
// graph_id SORTED: wave processes a contiguous node chunk (lane = dim),
// per-graph partial sum in register, one coalesced 256B atomicAdd flush per
// graph-change / chunk-end (R10-proven contention profile).
__global__ __launch_bounds__(256) void finish_kernel(
    const float* __restrict__ S, const float* __restrict__ Hn,
    const int* __restrict__ cnt8, const int* __restrict__ graph_id,
    float* __restrict__ H, float* __restrict__ gsum, float* __restrict__ gcnt,
    int M) {
    int lane = threadIdx.x & 63;
    int wid  = blockIdx.x * 4 + (threadIdx.x >> 6);   // global wave id
    int nw   = gridDim.x * 4;
    int cpw  = (M + nw - 1) / nw;
    int n0 = wid * cpw, n1 = min(n0 + cpw, M);
    if (n0 >= n1) return;

    float acc = 0.f;
    int cnt = 0;
    int cur = graph_id[n0];
    for (int n = n0; n < n1; ++n) {
        int gid = graph_id[n];
        if (gid != cur) {
            atomicAdd(&gsum[cur * DH + lane], acc);
            if (lane == 0) atomicAdd(&gcnt[cur], (float)cnt);
            acc = 0.f; cnt = 0; cur = gid;
        }
        float inv = 1.f / fmaxf((float)deg8(cnt8, n), 1.f);
        size_t o = (size_t)n * DH + lane;
        float val = fmaf(Hn[o], inv, S[o]);
        H[o] = val;
        acc += val;
        ++cnt;
    }
    atomicAdd(&gsum[cur * DH + lane], acc);
    if (lane == 0) atomicAdd(&gcnt[cur], (float)cnt);
}

// single block of 1024: out_feat = gsum/cnt ; out = out_feat @ W_cls + b_cls
// (own dispatch: stream-ordered after finish — no ticket, no fences)
__global__ __launch_bounds__(1024) void readout_kernel(
    const float* __restrict__ gsum, const float* __restrict__ gcnt,
    const float* __restrict__ Wc, const float* __restrict__ bc,
    float* __restrict__ out, float* __restrict__ out_feat) {
    __shared__ float ofs[NG][DH];
    int tid = threadIdx.x;
    int g = tid >> 6, d = tid & 63;
    float of = gsum[tid] / fmaxf(gcnt[g], 1.0f);
    out_feat[tid] = of;
    ofs[g][d] = of;
    __syncthreads();
    if (tid < NG * 2) {
        int gg = tid >> 1, cc = tid & 1;
        float acc = bc[cc];
#pragma unroll 8
        for (int dd = 0; dd < DH; ++dd) acc += ofs[gg][dd] * Wc[dd * 2 + cc];
        out[gg * 2 + cc] = acc;
    }
}

extern "C" void kernel_launch(void* const* d_in, const int* in_sizes, int n_in,
                              void* d_out, int out_size, void* d_ws, size_t ws_size,
                              hipStream_t stream) {
    const float* feat     = (const float*)d_in[0];
    const int*   src      = (const int*)d_in[1];
    const int*   dst      = (const int*)d_in[2];
    const int*   graph_id = (const int*)d_in[3];
    const float* Ws1 = (const float*)d_in[4];
    const float* Wn1 = (const float*)d_in[5];
    const float* b1  = (const float*)d_in[6];
    const float* Ws2 = (const float*)d_in[7];
    const float* Wn2 = (const float*)d_in[8];
    const float* b2  = (const float*)d_in[9];
    const float* Ws3 = (const float*)d_in[10];
    const float* Wn3 = (const float*)d_in[11];
    const float* b3  = (const float*)d_in[12];
    const float* Wc  = (const float*)d_in[13];
    const float* bc  = (const float*)d_in[14];

    const int M  = in_sizes[3];     // 10000 nodes
    const int E  = in_sizes[1];     // 320000 edges
    const int M2 = M * NSB;         // 80000 (dst,bucket) rows
    const int npb8 = (M + NSB - 1) / NSB;   // 1250 (<= MAXNPB)

    float* out      = (float*)d_out;             // 16 x 2
    float* out_feat = out + NG * 2;              // 16 x 64
    float* Hbuf     = out_feat + NG * DH;        // 10000 x 64 (final h)

    // workspace layout (256B-aligned carves)
    char* w = (char*)d_ws;
    size_t off = 0;
    auto carve = [&](size_t bytes) {
        size_t o = off;
        off = (off + bytes + 255) & ~(size_t)255;
        return o;
    };
    int*   cnt8  = (int*)  (w + carve((size_t)M2 * 4));
    float* gsum  = (float*)(w + carve((size_t)NG * DH * 4));
    float* gcnt  = (float*)(w + carve((size_t)NG * 4));
    size_t zero_bytes = off;                       // cnt8 + gsum + gcnt
    int*   es    = (int*)  (w + carve((size_t)M2 * CAP * 4));   // 10.24 MB
    float* Sbuf  = (float*)(w + carve((size_t)M * DH * 4));
    unsigned short* Pbuf = (unsigned short*)(w + carve((size_t)M * DH * 2));
    float* Hn    = (float*)(w + carve((size_t)M * DH * 4));
    (void)ws_size; (void)n_in; (void)out_size;

    (void)hipMemsetAsync(d_ws, 0, zero_bytes, stream);

    int gb = (M + 63) / 64;          // 157 gemm blocks
    int eb = (E + 511) / 512;        // 625 build blocks (512 thr)
    int ab = NSB * DTILES;           // 256 agg blocks (1/CU)
    int fb = 160;                    // finish blocks: 640 waves

    // layer 1 (K=256, split-K) + CSR build, ONE dispatch (independent outputs)
    gemm1_build_kernel<<<gb + eb, 512, 0, stream>>>(
        feat, Ws1, Wn1, b1, Sbuf, Pbuf, Hn,
        src, dst, cnt8, es, M, E, npb8, gb);
    agg_kernel<<<ab, 1024, 0, stream>>>(Pbuf, cnt8, es, Hn, M, npb8);

    // layer 2 (K=64, split-kk): X = relu(S1 + Hn1/deg) fused
    gemm_dual_kernel<<<gb, 512, 0, stream>>>(
        Sbuf, Ws2, Wn2, b2, Hn, cnt8, Sbuf, Pbuf, Hn, M);
    agg_kernel<<<ab, 1024, 0, stream>>>(Pbuf, cnt8, es, Hn, M, npb8);

    // layer 3 (K=64, split-kk): X = relu(S2 + Hn2/deg) fused
    gemm_dual_kernel<<<gb, 512, 0, stream>>>(
        Sbuf, Ws3, Wn3, b3, Hn, cnt8, Sbuf, Pbuf, Hn, M);
    agg_kernel<<<ab, 1024, 0, stream>>>(Pbuf, cnt8, es, Hn, M, npb8);

    // finish layer 3 (no relu) + readout accumulation
    finish_kernel<<<fb, 256, 0, stream>>>(Sbuf, Hn, cnt8, graph_id,
                                          Hbuf, gsum, gcnt, M);
    // readout: own dispatch, stream-ordered (no ticket/fence constructs)
    readout_kernel<<<1, 1024, 0, stream>>>(gsum, gcnt, Wc, bc, out, out_feat);
}